// Round 1
// baseline (674.037 us; speedup 1.0000x reference)
//
#include <hip/hip_runtime.h>
#include <stdint.h>

// NNCLR forward on MI355X.
// Inputs (fp32): projections_1 [512,256], projections_2 [512,256], feature_queue [65536,256] (pre-normalized)
// Outputs (fp32, concat flat): loss [2048], new_queue [65536,256]
//
// Pipeline:
//  k1_normalize : P = l2norm([p1;p2]) -> ws.Pn [1024,256] + ws.PnT [256,1024]; p1n also -> new_queue[0:512]
//  k2_nn        : fp32 argmax over P·Qᵀ (the 34.4-GFLOP hot loop), fused queue->new_queue copy.
//                 Per-WG candidates (packed u64) -> ws.cand[1024 rows][1024 wgs]
//  k2b_reduce   : reduce cand -> ws.nnidx[1024]
//  k3_sim       : S1 = 10*nn1·p2ᵀ, S2 = 10*nn2·p1ᵀ  [512,512] each -> ws.S
//  k4_loss      : loss rows = LSE(row/col of S) - diag
//
// fp32 similarities on purpose: argmax flip vs np-fp32 reference needs error << top1-top2 gap (~0.013);
// bf16 MFMA (~3e-4) would flip ~dozens of rows. fp32 VALU error ~1e-7 is safe.

#define BATCH  512
#define DIM    256
#define QUEUE  65536
#define MROWS  1024          // 2*BATCH stacked p-rows
#define NT     64            // queue rows per workgroup in k2
#define NWG    (QUEUE / NT)  // 1024 workgroups

__device__ __forceinline__ unsigned int mono_f32(float f) {
    unsigned int u = __float_as_uint(f);
    return (u & 0x80000000u) ? ~u : (u | 0x80000000u);  // monotone map: float order -> uint order
}

// ---------------- k1: normalize ----------------
__global__ void k1_normalize(const float* __restrict__ p1, const float* __restrict__ p2,
                             float* __restrict__ Pn, float* __restrict__ PnT,
                             float* __restrict__ outq)
{
    const int r = blockIdx.x;        // 0..1023 (0..511 = p1, 512..1023 = p2)
    const int t = threadIdx.x;       // 0..63, one wave per row
    const float* src = (r < BATCH) ? p1 : p2;
    const int row = (r < BATCH) ? r : r - BATCH;
    float4 v = ((const float4*)(src + (size_t)row * DIM))[t];
    float sq = v.x*v.x + v.y*v.y + v.z*v.z + v.w*v.w;
    #pragma unroll
    for (int off = 32; off; off >>= 1) sq += __shfl_xor(sq, off, 64);
    sq = fmaxf(sq, 1e-12f);
    float s = rsqrtf(sq);
    s = s * (1.5f - 0.5f * sq * s * s);   // Newton step: match fp32-exact rsqrt closely
    v.x *= s; v.y *= s; v.z *= s; v.w *= s;
    ((float4*)(Pn + (size_t)r * DIM))[t] = v;
    const int k = t * 4;
    PnT[(size_t)(k + 0) * MROWS + r] = v.x;
    PnT[(size_t)(k + 1) * MROWS + r] = v.y;
    PnT[(size_t)(k + 2) * MROWS + r] = v.z;
    PnT[(size_t)(k + 3) * MROWS + r] = v.w;
    if (r < BATCH) ((float4*)(outq + (size_t)r * DIM))[t] = v;  // new_queue[0:512] = p1n
}

// ---------------- k2: NN search (hot) ----------------
// LDS: Qt[k=256][n=64] fp32 = 64 KB -> 2 blocks/CU. Per-thread 8m x 4n register tile.
__global__ __launch_bounds__(256, 2)
void k2_nn(const float* __restrict__ Pn, const float* __restrict__ queue,
           float* __restrict__ outq, unsigned long long* __restrict__ cand)
{
    __shared__ float Qt[DIM * NT];   // [k][n], 65536 B
    const int wg  = blockIdx.x;      // 0..1023
    const int n0  = wg * NT;
    const int tid = threadIdx.x;

    // Stage queue tile (transpose into LDS) + fused copy to new_queue rows 512..65536.
    // Mapping row=idx&63: LDS writes conflict-free (bank = row mod 32); global side is
    // gather-y per instr but the 4 waves collectively consume full lines -> HBM traffic exact.
    #pragma unroll
    for (int it = 0; it < 16; ++it) {
        int idx = tid + it * 256;
        int row = idx & 63;
        int k4  = idx >> 6;          // 0..63
        float4 v = ((const float4*)(queue + (size_t)(n0 + row) * DIM))[k4];
        Qt[(k4 * 4 + 0) * NT + row] = v.x;
        Qt[(k4 * 4 + 1) * NT + row] = v.y;
        Qt[(k4 * 4 + 2) * NT + row] = v.z;
        Qt[(k4 * 4 + 3) * NT + row] = v.w;
        int qrow = n0 + row;
        if (qrow < QUEUE - BATCH)
            ((float4*)(outq + (size_t)(qrow + BATCH) * DIM))[k4] = v;
    }
    __syncthreads();

    const int tx = tid & 15;         // n-group: n = n0 + 4*tx + j
    const int ty = tid >> 4;         // m-group: m = m0 + 8*ty + i
    const float4* Pn4 = (const float4*)Pn;
    const float4* Qt4 = (const float4*)Qt;

    for (int mt = 0; mt < MROWS / 128; ++mt) {   // 8 m-tiles of 128
        const int m0 = mt * 128;
        float acc[8][4];
        #pragma unroll
        for (int i = 0; i < 8; ++i)
            #pragma unroll
            for (int j = 0; j < 4; ++j) acc[i][j] = 0.f;

        for (int k4 = 0; k4 < 64; ++k4) {
            float4 bv[4];                        // bv[kk] = Qt[k4*4+kk][4tx..4tx+3]
            #pragma unroll
            for (int kk = 0; kk < 4; ++kk)
                bv[kk] = Qt4[(k4 * 4 + kk) * (NT / 4) + tx];
            float4 a[8];
            #pragma unroll
            for (int i = 0; i < 8; ++i)
                a[i] = Pn4[(size_t)(m0 + ty * 8 + i) * (DIM / 4) + k4];
            #pragma unroll
            for (int i = 0; i < 8; ++i) {
                float av[4] = {a[i].x, a[i].y, a[i].z, a[i].w};
                #pragma unroll
                for (int kk = 0; kk < 4; ++kk) {
                    acc[i][0] = fmaf(av[kk], bv[kk].x, acc[i][0]);
                    acc[i][1] = fmaf(av[kk], bv[kk].y, acc[i][1]);
                    acc[i][2] = fmaf(av[kk], bv[kk].z, acc[i][2]);
                    acc[i][3] = fmaf(av[kk], bv[kk].w, acc[i][3]);
                }
            }
        }

        // Per-row argmax candidate for this WG. Pack (mono(val)<<32)|(65535-n): max -> first-index tie-break.
        #pragma unroll
        for (int i = 0; i < 8; ++i) {
            unsigned long long best = 0ull;
            #pragma unroll
            for (int j = 0; j < 4; ++j) {
                unsigned long long pk = ((unsigned long long)mono_f32(acc[i][j]) << 32)
                                      | (unsigned int)(65535 - (n0 + tx * 4 + j));
                best = best > pk ? best : pk;
            }
            #pragma unroll
            for (int off = 1; off <= 8; off <<= 1) {   // reduce across the 16 tx lanes
                unsigned long long o = __shfl_xor(best, off, 64);
                best = best > o ? best : o;
            }
            if (tx == 0)
                cand[(size_t)(m0 + ty * 8 + i) * NWG + wg] = best;
        }
    }
}

// ---------------- k2b: reduce candidates ----------------
__global__ void k2b_reduce(const unsigned long long* __restrict__ cand, int* __restrict__ nnidx)
{
    const int row = blockIdx.x;      // 0..1023
    const int tid = threadIdx.x;     // 256
    unsigned long long best = 0ull;
    for (int i = tid; i < NWG; i += 256) {
        unsigned long long c = cand[(size_t)row * NWG + i];
        best = best > c ? best : c;
    }
    #pragma unroll
    for (int off = 1; off < 64; off <<= 1) {
        unsigned long long o = __shfl_xor(best, off, 64);
        best = best > o ? best : o;
    }
    __shared__ unsigned long long red[4];
    if ((tid & 63) == 0) red[tid >> 6] = best;
    __syncthreads();
    if (tid == 0) {
        #pragma unroll
        for (int w = 1; w < 4; ++w) best = best > red[w] ? best : red[w];
        nnidx[row] = 65535 - (int)(best & 0xFFFFull);
    }
}

// ---------------- k3: S1/S2 similarity matrices ----------------
__global__ void k3_sim(const int* __restrict__ nnidx, const float* __restrict__ queue,
                       const float* __restrict__ PnT, float* __restrict__ S)
{
    const int b = blockIdx.x;        // 0..1023: [0,512) -> S1 rows, [512,1024) -> S2 rows
    const int tid = threadIdx.x;     // 256
    const int which = (b < BATCH) ? 0 : 1;
    const int i = which ? b - BATCH : b;
    const int idx = nnidx[which ? BATCH + i : i];
    const int colbase = which ? 0 : BATCH;   // S1 vs p2 (P cols 512..1023), S2 vs p1 (0..511)
    __shared__ float nnv[DIM];
    nnv[tid] = queue[(size_t)idx * DIM + tid];   // blockDim == DIM
    __syncthreads();
    float acc0 = 0.f, acc1 = 0.f;
    #pragma unroll 4
    for (int k = 0; k < DIM; ++k) {
        const float nv = nnv[k];
        const float* rowp = PnT + (size_t)k * MROWS + colbase;
        acc0 = fmaf(nv, rowp[tid], acc0);
        acc1 = fmaf(nv, rowp[tid + 256], acc1);
    }
    float* Sout = S + (size_t)which * (BATCH * BATCH) + (size_t)i * BATCH;
    Sout[tid]       = acc0 * 10.0f;   // /TEMPERATURE
    Sout[tid + 256] = acc1 * 10.0f;
}

// ---------------- k4: loss ----------------
__global__ void k4_loss(const float* __restrict__ S, float* __restrict__ loss)
{
    const int r = blockIdx.x;        // 0..2047
    const int tid = threadIdx.x;     // 256
    const int grp = r >> 9;          // 0:S1 rows, 1:S1 cols, 2:S2 rows, 3:S2 cols
    const int i = r & 511;
    const float* M = S + (size_t)(grp >> 1) * (BATCH * BATCH);
    float x0, x1;
    if (!(grp & 1)) { x0 = M[(size_t)i * BATCH + tid];  x1 = M[(size_t)i * BATCH + tid + 256]; }
    else            { x0 = M[(size_t)tid * BATCH + i];  x1 = M[(size_t)(tid + 256) * BATCH + i]; }
    const float diag = M[(size_t)i * BATCH + i];

    float mx = fmaxf(x0, x1);
    #pragma unroll
    for (int off = 1; off < 64; off <<= 1) mx = fmaxf(mx, __shfl_xor(mx, off, 64));
    __shared__ float redm[4], reds[4];
    if ((tid & 63) == 0) redm[tid >> 6] = mx;
    __syncthreads();
    mx = fmaxf(fmaxf(redm[0], redm[1]), fmaxf(redm[2], redm[3]));

    float e = __expf(x0 - mx) + __expf(x1 - mx);
    #pragma unroll
    for (int off = 1; off < 64; off <<= 1) e += __shfl_xor(e, off, 64);
    if ((tid & 63) == 0) reds[tid >> 6] = e;
    __syncthreads();
    if (tid == 0)
        loss[r] = mx + logf(reds[0] + reds[1] + reds[2] + reds[3]) - diag;
}

// ---------------- launcher ----------------
extern "C" void kernel_launch(void* const* d_in, const int* in_sizes, int n_in,
                              void* d_out, int out_size, void* d_ws, size_t ws_size,
                              hipStream_t stream)
{
    const float* p1    = (const float*)d_in[0];
    const float* p2    = (const float*)d_in[1];
    const float* queue = (const float*)d_in[2];
    float* out  = (float*)d_out;
    float* loss = out;                 // [2048]
    float* outq = out + 4 * BATCH;     // new_queue [65536,256]

    // Workspace layout (~12.1 MB total)
    char* w = (char*)d_ws;
    unsigned long long* cand = (unsigned long long*)w;                 // 1024*1024*8 = 8 MB
    float* Pn  = (float*)(w + (size_t)MROWS * NWG * sizeof(unsigned long long));
    float* PnT = Pn  + (size_t)MROWS * DIM;                            // 1 MB each
    float* S   = PnT + (size_t)DIM * MROWS;                            // 2 MB
    int* nnidx = (int*)(S + 2 * BATCH * BATCH);                        // 4 KB

    hipLaunchKernelGGL(k1_normalize, dim3(MROWS), dim3(64), 0, stream, p1, p2, Pn, PnT, outq);
    hipLaunchKernelGGL(k2_nn,       dim3(NWG),   dim3(256), 0, stream, Pn, queue, outq, cand);
    hipLaunchKernelGGL(k2b_reduce,  dim3(MROWS), dim3(256), 0, stream, cand, nnidx);
    hipLaunchKernelGGL(k3_sim,      dim3(MROWS), dim3(256), 0, stream, nnidx, queue, PnT, S);
    hipLaunchKernelGGL(k4_loss,     dim3(4 * BATCH), dim3(256), 0, stream, S, loss);
}